// Round 9
// baseline (276.286 us; speedup 1.0000x reference)
//
#include <hip/hip_runtime.h>
#include <hip/hip_cooperative_groups.h>
#include <math.h>

namespace cg = cooperative_groups;

#define F_IN  128
#define F_OUT 256
#define GBITS 5            // 32 nodes per group
#define G_MAX 380          // max groups (G = ceil(n/32) = 375 for n=12000)
#define WPR   376          // padded words per LDS bitmap row (>= ceil(n/32))
#define NBLK  256          // edge-pass blocks

// ---------------------------------------------------------------------------
// Mega-kernel: the whole pipeline in one cooperative launch.
// Phases (separated by grid.sync()):
//  P1 count      (blocks 0..255): per-block group histogram -> counts_t[g][b]
//  P2 scan       (blocks 0..G-1): per-group exclusive scan  -> off_t, gtot
//  P3 scatter    (blocks 0..255): local scan gtot->base; LDS cursors; bucket
//  P4 dedup      (blocks 0..G-1): LDS bitmap dedup -> popcount -> dinv; colsum
//  P5 s-reduce   (blocks 0..31) : s4[j] = sum_g partial4[g][j]
//  P6 gemv+outer (all blocks)   : agg[f]=s·W[:,f]; out = dinv*agg + bias
// All atomics are integer/idempotent or in LDS; float sums are fixed-order
// => bitwise deterministic.
// ---------------------------------------------------------------------------
struct DD {
    unsigned bm[32 * WPR];     // 48128 B
    float    dloc[32];
    float4   red[8][32];
};
union SharedU {
    int hist[G_MAX];
    int row[NBLK];
    struct { int cur[G_MAX]; int sc[512]; } sct;
    DD dd;                     // 52352 B (dominant)
    float4 sred[256];
    float  s[F_IN];
};

__global__ __launch_bounds__(256)
void k_mega(const int* __restrict__ ei, int E, int n, int G,
            const float4* __restrict__ x4,
            const float* __restrict__ W,
            const float* __restrict__ bias,
            int* __restrict__ counts_t,    // [G][NBLK]
            int* __restrict__ off_t,       // [G][NBLK]
            int* __restrict__ gtot,        // [G]
            int* __restrict__ gbase,       // [G]
            int* __restrict__ gend,        // [G]
            unsigned* __restrict__ bucket, // [2E]
            float* __restrict__ dinv,      // [n]
            float4* __restrict__ partial4, // [G][32]
            float4* __restrict__ s4g,      // [32]
            float4* __restrict__ out4)     // [n*64]
{
    cg::grid_group grid = cg::this_grid();
    __shared__ SharedU sh;
    const int blk = blockIdx.x, t = threadIdx.x;

    // ---------------- P1: count ----------------
    if (blk < NBLK) {
        for (int g = t; g < G; g += 256) sh.hist[g] = 0;
        __syncthreads();
        int C = (E + NBLK - 1) / NBLK;
        int e0 = blk * C, e1 = min(E, e0 + C);
        for (int e = e0 + t; e < e1; e += 256) {
            int a = ei[e], c = ei[E + e];
            atomicAdd(&sh.hist[a >> GBITS], 1);
            atomicAdd(&sh.hist[c >> GBITS], 1);
        }
        __syncthreads();
        for (int g = t; g < G; g += 256)
            counts_t[(size_t)g * NBLK + blk] = sh.hist[g];
    }
    grid.sync();

    // ---------------- P2: per-group scan over edge-blocks ----------------
    if (blk < G) {
        int c = counts_t[(size_t)blk * NBLK + t];
        sh.row[t] = c;
        __syncthreads();
        for (int d = 1; d < NBLK; d <<= 1) {
            int v = (t >= d) ? sh.row[t - d] : 0;
            __syncthreads();
            sh.row[t] += v;
            __syncthreads();
        }
        off_t[(size_t)blk * NBLK + t] = sh.row[t] - c;   // exclusive
        if (t == NBLK - 1) gtot[blk] = sh.row[t];
    }
    grid.sync();

    // ---------------- P3: scatter ----------------
    if (blk < NBLK) {
        int i1 = t + 256;
        int c0 = (t  < G) ? gtot[t]  : 0;
        int c1 = (i1 < G) ? gtot[i1] : 0;
        sh.sct.sc[t] = c0; sh.sct.sc[i1] = c1;
        __syncthreads();
        for (int d = 1; d < 512; d <<= 1) {
            int v0 = (t  >= d) ? sh.sct.sc[t  - d] : 0;
            int v1 = (i1 >= d) ? sh.sct.sc[i1 - d] : 0;
            __syncthreads();
            sh.sct.sc[t] += v0; sh.sct.sc[i1] += v1;
            __syncthreads();
        }
        // sc now holds the inclusive scan of gtot; base = incl - tot
        if (t < G)
            sh.sct.cur[t]  = off_t[(size_t)t  * NBLK + blk] + sh.sct.sc[t]  - c0;
        if (i1 < G)
            sh.sct.cur[i1] = off_t[(size_t)i1 * NBLK + blk] + sh.sct.sc[i1] - c1;
        if (blk == 0) {
            if (t < G)  { gbase[t]  = sh.sct.sc[t]  - c0; gend[t]  = sh.sct.sc[t];  }
            if (i1 < G) { gbase[i1] = sh.sct.sc[i1] - c1; gend[i1] = sh.sct.sc[i1]; }
        }
        __syncthreads();
        int C = (E + NBLK - 1) / NBLK;
        int e0 = blk * C, e1 = min(E, e0 + C);
        for (int e = e0 + t; e < e1; e += 256) {
            int a = ei[e], c = ei[E + e];
            int s1 = atomicAdd(&sh.sct.cur[a >> GBITS], 1);
            bucket[s1] = ((unsigned)(a & 31) << 16) | (unsigned)c;
            int s2 = atomicAdd(&sh.sct.cur[c >> GBITS], 1);
            bucket[s2] = ((unsigned)(c & 31) << 16) | (unsigned)a;
        }
    }
    grid.sync();

    // ---------------- P4: dedup + popcount + colsum ----------------
    if (blk < G) {
        for (int i = t; i < 32 * WPR; i += 256) sh.dd.bm[i] = 0;
        __syncthreads();
        int i0 = gbase[blk], i1e = gend[blk];
        for (int i = i0 + t; i < i1e; i += 256) {
            unsigned w = bucket[i];
            atomicOr(&sh.dd.bm[(w >> 16) * WPR + ((w & 0xFFFFu) >> 5)],
                     1u << (w & 31));
        }
        __syncthreads();
        int wave = t >> 6, lane = t & 63;
        int words = (n + 31) >> 5;
        for (int lr = wave; lr < 32; lr += 4) {
            int node = blk * 32 + lr;
            int cnt = 0;
            for (int w = lane; w < words; w += 64)
                cnt += __popc(sh.dd.bm[lr * WPR + w]);
            #pragma unroll
            for (int o = 32; o > 0; o >>= 1)
                cnt += __shfl_down(cnt, o, 64);
            if (lane == 0) {
                float dv = 1.0f / sqrtf((float)cnt);   // deg==0 -> inf (matches ref)
                sh.dd.dloc[lr] = dv;
                if (node < n) dinv[node] = dv;
            }
        }
        __syncthreads();
        int c4 = t & 31, ro = t >> 5;
        float4 acc = make_float4(0.f, 0.f, 0.f, 0.f);
        for (int lr = ro; lr < 32; lr += 8) {
            int node = blk * 32 + lr;
            if (node >= n) break;
            float dv = sh.dd.dloc[lr];
            float4 v = x4[(size_t)node * (F_IN / 4) + c4];
            acc.x += dv * v.x; acc.y += dv * v.y;
            acc.z += dv * v.z; acc.w += dv * v.w;
        }
        sh.dd.red[ro][c4] = acc;
        __syncthreads();
        if (ro == 0) {
            float4 s = sh.dd.red[0][c4];
            #pragma unroll
            for (int k = 1; k < 8; ++k) {
                float4 v = sh.dd.red[k][c4];
                s.x += v.x; s.y += v.y; s.z += v.z; s.w += v.w;
            }
            partial4[(size_t)blk * (F_IN / 4) + c4] = s;
        }
    }
    grid.sync();

    // ---------------- P5: s4[j] = sum_g partial4[g][j] ----------------
    if (blk < F_IN / 4) {
        float4 acc = make_float4(0.f, 0.f, 0.f, 0.f);
        for (int g = t; g < G; g += 256) {
            float4 v = partial4[(size_t)g * (F_IN / 4) + blk];
            acc.x += v.x; acc.y += v.y; acc.z += v.z; acc.w += v.w;
        }
        sh.sred[t] = acc;
        __syncthreads();
        for (int st = 128; st > 0; st >>= 1) {
            if (t < st) {
                float4 o = sh.sred[t + st];
                float4 v = sh.sred[t];
                v.x += o.x; v.y += o.y; v.z += o.z; v.w += o.w;
                sh.sred[t] = v;
            }
            __syncthreads();
        }
        if (t == 0) s4g[blk] = sh.sred[0];
    }
    grid.sync();

    // ---------------- P6: gemv (agg = s·W) fused with outer write ----------------
    {
        if (t < F_IN / 4) ((float4*)sh.s)[t] = s4g[t];
        __syncthreads();
        int total4 = n * (F_OUT / 4);
        int gs = (int)gridDim.x * 256;          // multiple of 64 always
        int i0 = blk * 256 + t;
        int f4 = i0 & 63;                       // constant across grid-stride iters
        const float4* W4 = (const float4*)W;
        float4 a = make_float4(0.f, 0.f, 0.f, 0.f);
        #pragma unroll 8
        for (int k = 0; k < F_IN; ++k) {
            float sk = sh.s[k];
            float4 w = W4[(size_t)k * (F_OUT / 4) + f4];
            a.x += sk * w.x; a.y += sk * w.y;
            a.z += sk * w.z; a.w += sk * w.w;
        }
        float4 b4 = ((const float4*)bias)[f4];
        for (int i = i0; i < total4; i += gs) {
            float d = dinv[i >> 6];             // 64 consecutive lanes share node
            float4 o;
            o.x = fmaf(d, a.x, b4.x);
            o.y = fmaf(d, a.y, b4.y);
            o.z = fmaf(d, a.z, b4.z);
            o.w = fmaf(d, a.w, b4.w);
            out4[i] = o;
        }
    }
}

// ===========================================================================
// Fallback multi-kernel path (round-8, verified) — used if cooperative launch
// is unavailable or the fast-path preconditions fail.
// ===========================================================================
__global__ __launch_bounds__(256)
void k_count(const int* __restrict__ ei, int E, int G,
             int* __restrict__ counts_t) {
    __shared__ int hist[G_MAX];
    int b = blockIdx.x, t = threadIdx.x;
    for (int g = t; g < G; g += 256) hist[g] = 0;
    __syncthreads();
    int C = (E + (int)gridDim.x - 1) / (int)gridDim.x;
    int e0 = b * C, e1 = min(E, e0 + C);
    for (int e = e0 + t; e < e1; e += 256) {
        int a = ei[e], c = ei[E + e];
        atomicAdd(&hist[a >> GBITS], 1);
        atomicAdd(&hist[c >> GBITS], 1);
    }
    __syncthreads();
    for (int g = t; g < G; g += 256)
        counts_t[(size_t)g * NBLK + b] = hist[g];
}

__global__ __launch_bounds__(NBLK)
void k_prefix1(const int* __restrict__ counts_t, int G,
               int* __restrict__ off_t, int* __restrict__ tot) {
    __shared__ int s[NBLK];
    int g = blockIdx.x, t = threadIdx.x;
    int c = counts_t[(size_t)g * NBLK + t];
    s[t] = c;
    __syncthreads();
    #pragma unroll
    for (int d = 1; d < NBLK; d <<= 1) {
        int v = (t >= d) ? s[t - d] : 0;
        __syncthreads();
        s[t] += v;
        __syncthreads();
    }
    off_t[(size_t)g * NBLK + t] = s[t] - c;
    if (t == NBLK - 1) tot[g] = s[t];
}

__global__ __launch_bounds__(512)
void k_prefix2(const int* __restrict__ tot, int G,
               int* __restrict__ base, int* __restrict__ endg) {
    __shared__ int s[512];
    int t = threadIdx.x;
    int c = (t < G) ? tot[t] : 0;
    s[t] = c;
    __syncthreads();
    #pragma unroll
    for (int d = 1; d < 512; d <<= 1) {
        int v = (t >= d) ? s[t - d] : 0;
        __syncthreads();
        s[t] += v;
        __syncthreads();
    }
    if (t < G) { base[t] = s[t] - c; endg[t] = s[t]; }
}

__global__ __launch_bounds__(256)
void k_scatter(const int* __restrict__ ei, int E, int G,
               const int* __restrict__ off_t, const int* __restrict__ base,
               unsigned* __restrict__ bucket) {
    __shared__ int cur[G_MAX];
    int b = blockIdx.x, t = threadIdx.x;
    for (int g = t; g < G; g += 256)
        cur[g] = off_t[(size_t)g * NBLK + b] + base[g];
    __syncthreads();
    int C = (E + (int)gridDim.x - 1) / (int)gridDim.x;
    int e0 = b * C, e1 = min(E, e0 + C);
    for (int e = e0 + t; e < e1; e += 256) {
        int a = ei[e], c = ei[E + e];
        int s1 = atomicAdd(&cur[a >> GBITS], 1);
        bucket[s1] = ((unsigned)(a & 31) << 16) | (unsigned)c;
        int s2 = atomicAdd(&cur[c >> GBITS], 1);
        bucket[s2] = ((unsigned)(c & 31) << 16) | (unsigned)a;
    }
}

__global__ __launch_bounds__(256)
void k_dedup_colsum(const unsigned* __restrict__ bucket,
                    const int* __restrict__ base, const int* __restrict__ endg,
                    const float4* __restrict__ x4,
                    float* __restrict__ dinv, float4* __restrict__ partial4,
                    int n) {
    __shared__ unsigned bm[32 * WPR];
    __shared__ float dloc[32];
    __shared__ float4 red[8][32];
    int g = blockIdx.x, t = threadIdx.x;
    for (int i = t; i < 32 * WPR; i += 256) bm[i] = 0;
    __syncthreads();
    int i0 = base[g], i1 = endg[g];
    for (int i = i0 + t; i < i1; i += 256) {
        unsigned w = bucket[i];
        atomicOr(&bm[(w >> 16) * WPR + ((w & 0xFFFFu) >> 5)], 1u << (w & 31));
    }
    __syncthreads();
    int wave = t >> 6, lane = t & 63;
    int words = (n + 31) >> 5;
    for (int lr = wave; lr < 32; lr += 4) {
        int node = g * 32 + lr;
        int cnt = 0;
        for (int w = lane; w < words; w += 64)
            cnt += __popc(bm[lr * WPR + w]);
        #pragma unroll
        for (int o = 32; o > 0; o >>= 1)
            cnt += __shfl_down(cnt, o, 64);
        if (lane == 0) {
            float dv = 1.0f / sqrtf((float)cnt);
            dloc[lr] = dv;
            if (node < n) dinv[node] = dv;
        }
    }
    __syncthreads();
    int c4 = t & 31, ro = t >> 5;
    float4 acc = make_float4(0.f, 0.f, 0.f, 0.f);
    for (int lr = ro; lr < 32; lr += 8) {
        int node = g * 32 + lr;
        if (node >= n) break;
        float dv = dloc[lr];
        float4 v = x4[(size_t)node * (F_IN / 4) + c4];
        acc.x += dv * v.x; acc.y += dv * v.y;
        acc.z += dv * v.z; acc.w += dv * v.w;
    }
    red[ro][c4] = acc;
    __syncthreads();
    if (ro == 0) {
        float4 s = red[0][c4];
        #pragma unroll
        for (int k = 1; k < 8; ++k) {
            float4 v = red[k][c4];
            s.x += v.x; s.y += v.y; s.z += v.z; s.w += v.w;
        }
        partial4[(size_t)g * (F_IN / 4) + c4] = s;
    }
}

__global__ __launch_bounds__(1024)
void k_reduce_agg(const float4* __restrict__ partial4, int nparts,
                  const float* __restrict__ W, float* __restrict__ agg) {
    __shared__ float4 lds[32][32];
    __shared__ float s[F_IN];
    __shared__ float aggLds[4][F_OUT];
    int t = threadIdx.x;
    int c4 = t & 31;
    int g  = t >> 5;
    {
        float4 acc = make_float4(0.f, 0.f, 0.f, 0.f);
        for (int b = g; b < nparts; b += 32) {
            float4 v = partial4[(size_t)b * (F_IN / 4) + c4];
            acc.x += v.x; acc.y += v.y; acc.z += v.z; acc.w += v.w;
        }
        lds[g][c4] = acc;
    }
    __syncthreads();
    for (int st = 16; st > 0; st >>= 1) {
        if (g < st) {
            float4 o = lds[g + st][c4];
            float4 v = lds[g][c4];
            v.x += o.x; v.y += o.y; v.z += o.z; v.w += o.w;
            lds[g][c4] = v;
        }
        __syncthreads();
    }
    if (g == 0) {
        float4 v = lds[0][c4];
        s[c4 * 4 + 0] = v.x; s[c4 * 4 + 1] = v.y;
        s[c4 * 4 + 2] = v.z; s[c4 * 4 + 3] = v.w;
    }
    __syncthreads();
    {
        int f  = t & 255;
        int kg = t >> 8;
        float acc = 0.f;
        #pragma unroll 8
        for (int k = kg * 32; k < kg * 32 + 32; ++k)
            acc += s[k] * W[(size_t)k * F_OUT + f];
        aggLds[kg][f] = acc;
    }
    __syncthreads();
    if (t < F_OUT)
        agg[t] = aggLds[0][t] + aggLds[1][t] + aggLds[2][t] + aggLds[3][t];
}

__global__ void k_outer(const float* __restrict__ dinv,
                        const float* __restrict__ agg,
                        const float* __restrict__ bias,
                        float4* __restrict__ out4, int n) {
    int i = blockIdx.x * blockDim.x + threadIdx.x;
    const int per_row = F_OUT / 4;
    int total = n * per_row;
    if (i >= total) return;
    int node = i >> 6;
    int f4   = i & 63;
    float d = dinv[node];
    float4 a  = ((const float4*)agg)[f4];
    float4 bb = ((const float4*)bias)[f4];
    float4 o;
    o.x = fmaf(d, a.x, bb.x);
    o.y = fmaf(d, a.y, bb.y);
    o.z = fmaf(d, a.z, bb.z);
    o.w = fmaf(d, a.w, bb.w);
    out4[i] = o;
}

// ---------------------------------------------------------------------------
static inline size_t align_up(size_t v, size_t a) { return (v + a - 1) & ~(a - 1); }

extern "C" void kernel_launch(void* const* d_in, const int* in_sizes, int n_in,
                              void* d_out, int out_size, void* d_ws, size_t ws_size,
                              hipStream_t stream) {
    const float* x    = (const float*)d_in[0];
    const int*   ei   = (const int*)  d_in[1];
    const float* W    = (const float*)d_in[2];
    const float* bias = (const float*)d_in[3];

    const int n = in_sizes[0] / F_IN;     // 12000
    int E = in_sizes[1] / 2;              // 384000
    const int G = (n + 31) >> GBITS;      // 375

    char* ws = (char*)d_ws;
    size_t off_b = 0;
    float* dinv = (float*)(ws + off_b); off_b = align_up(off_b + (size_t)n * 4, 256);
    float* agg  = (float*)(ws + off_b); off_b = align_up(off_b + (size_t)F_OUT * 4, 256);
    float4* partial4 = (float4*)(ws + off_b); off_b = align_up(off_b + (size_t)G * F_IN * 4, 256);
    int* counts_t = (int*)(ws + off_b); off_b = align_up(off_b + (size_t)G * NBLK * 4, 256);
    int* offs_t   = (int*)(ws + off_b); off_b = align_up(off_b + (size_t)G * NBLK * 4, 256);
    int* tot    = (int*)(ws + off_b); off_b = align_up(off_b + (size_t)G * 4, 256);
    int* base   = (int*)(ws + off_b); off_b = align_up(off_b + (size_t)G * 4, 256);
    int* endg   = (int*)(ws + off_b); off_b = align_up(off_b + (size_t)G * 4, 256);
    float4* s4g = (float4*)(ws + off_b); off_b = align_up(off_b + (size_t)(F_IN / 4) * 16, 256);
    unsigned* bucket = (unsigned*)(ws + off_b);
    size_t need = off_b + (size_t)2 * E * 4;

    bool fast = (G <= G_MAX) && (((n + 31) >> 5) <= WPR) && (n <= 65536) &&
                (need <= ws_size) && (G >= NBLK) && (G >= 32);

    if (fast) {
        int grid = G;                      // >= NBLK and >= 32
        void* args[] = {
            (void*)&ei, (void*)&E, (void*)&n, (void*)&G,
            (void*)&x, (void*)&W, (void*)&bias,
            (void*)&counts_t, (void*)&offs_t, (void*)&tot,
            (void*)&base, (void*)&endg, (void*)&bucket,
            (void*)&dinv, (void*)&partial4, (void*)&s4g, (void*)&d_out
        };
        hipError_t err = hipLaunchCooperativeKernel(
            reinterpret_cast<void*>(k_mega), dim3(grid), dim3(256),
            args, 0, stream);
        if (err == hipSuccess) return;
        // else fall through to multi-kernel path
    }

    if ((G <= G_MAX) && (((n + 31) >> 5) <= WPR) && (n <= 65536) && (need <= ws_size)) {
        k_count  <<<NBLK, 256, 0, stream>>>(ei, E, G, counts_t);
        k_prefix1<<<G,   NBLK, 0, stream>>>(counts_t, G, offs_t, tot);
        k_prefix2<<<1,    512, 0, stream>>>(tot, G, base, endg);
        k_scatter<<<NBLK, 256, 0, stream>>>(ei, E, G, offs_t, base, bucket);
        k_dedup_colsum<<<G, 256, 0, stream>>>(bucket, base, endg,
                                              (const float4*)x, dinv, partial4, n);
        k_reduce_agg<<<1, 1024, 0, stream>>>(partial4, G, W, agg);
        int total4 = n * (F_OUT / 4);
        k_outer<<<(total4 + 255) / 256, 256, 0, stream>>>(dinv, agg, bias,
                                                          (float4*)d_out, n);
    }
}

// Round 10
// 52.279 us; speedup vs baseline: 5.2848x; 5.2848x over previous
//
#include <hip/hip_runtime.h>
#include <math.h>

#define F_IN  128
#define F_OUT 256
#define GBITS 5            // 32 nodes per group
#define G_MAX 380          // max groups (G = ceil(n/32) = 375 for n=12000); must be <= 512
#define WPR   376          // padded words per LDS bitmap row (>= ceil(n/32))
#define NBLK  256          // edge-pass blocks (k_count / k_scatter must match)

// ---------------------------------------------------------------------------
// P1: per-block group histogram of incidences, written TRANSPOSED:
// counts_t[g*NBLK + b]. LDS atomics only.
// ---------------------------------------------------------------------------
__global__ __launch_bounds__(256)
void k_count(const int* __restrict__ ei, int E, int G,
             int* __restrict__ counts_t /* [G][NBLK] */) {
    __shared__ int hist[G_MAX];
    int b = blockIdx.x, t = threadIdx.x;
    for (int g = t; g < G; g += 256) hist[g] = 0;
    __syncthreads();
    int C = (E + (int)gridDim.x - 1) / (int)gridDim.x;
    int e0 = b * C, e1 = min(E, e0 + C);
    for (int e = e0 + t; e < e1; e += 256) {
        int a = ei[e], c = ei[E + e];
        atomicAdd(&hist[a >> GBITS], 1);
        atomicAdd(&hist[c >> GBITS], 1);
    }
    __syncthreads();
    for (int g = t; g < G; g += 256)
        counts_t[(size_t)g * NBLK + b] = hist[g];
}

// ---------------------------------------------------------------------------
// P2: per-group exclusive scan over the NBLK per-block counts.
// One block per group; coalesced 256-int load; Hillis-Steele in LDS.
// off_t[g*NBLK+b] = sum_{b'<b} counts_t[g][b'];  gtot[g] = group total.
// ---------------------------------------------------------------------------
__global__ __launch_bounds__(NBLK)
void k_prefix1(const int* __restrict__ counts_t, int G,
               int* __restrict__ off_t, int* __restrict__ gtot) {
    __shared__ int s[NBLK];
    int g = blockIdx.x, t = threadIdx.x;
    int c = counts_t[(size_t)g * NBLK + t];
    s[t] = c;
    __syncthreads();
    #pragma unroll
    for (int d = 1; d < NBLK; d <<= 1) {
        int v = (t >= d) ? s[t - d] : 0;
        __syncthreads();
        s[t] += v;
        __syncthreads();
    }
    off_t[(size_t)g * NBLK + t] = s[t] - c;      // exclusive
    if (t == NBLK - 1) gtot[g] = s[t];
}

// ---------------------------------------------------------------------------
// P3: scatter incidences into group buckets. Each block locally scans
// gtot[0..G) (512-wide Hillis-Steele, 2 elems/thread) to get group bases —
// removes the separate k_prefix2 launch. Block 0 publishes gbase/gend for
// the dedup kernel. Cursors in LDS. pack = (node&31)<<16 | other.
// (Scan+cursor logic verified in round 9's mega-kernel: same absmax.)
// ---------------------------------------------------------------------------
__global__ __launch_bounds__(256)
void k_scatter(const int* __restrict__ ei, int E, int G,
               const int* __restrict__ off_t, const int* __restrict__ gtot,
               int* __restrict__ gbase, int* __restrict__ gend,
               unsigned* __restrict__ bucket) {
    __shared__ int cur[G_MAX];
    __shared__ int sc[512];
    int b = blockIdx.x, t = threadIdx.x;
    int i1 = t + 256;
    int c0 = (t  < G) ? gtot[t]  : 0;
    int c1 = (i1 < G) ? gtot[i1] : 0;
    sc[t] = c0; sc[i1] = c1;
    __syncthreads();
    for (int d = 1; d < 512; d <<= 1) {
        int v0 = (t  >= d) ? sc[t  - d] : 0;
        int v1 = (i1 >= d) ? sc[i1 - d] : 0;
        __syncthreads();
        sc[t] += v0; sc[i1] += v1;
        __syncthreads();
    }
    // sc = inclusive scan of gtot; base = incl - tot
    if (t < G)
        cur[t]  = off_t[(size_t)t  * NBLK + b] + sc[t]  - c0;
    if (i1 < G)
        cur[i1] = off_t[(size_t)i1 * NBLK + b] + sc[i1] - c1;
    if (b == 0) {
        if (t < G)  { gbase[t]  = sc[t]  - c0; gend[t]  = sc[t];  }
        if (i1 < G) { gbase[i1] = sc[i1] - c1; gend[i1] = sc[i1]; }
    }
    __syncthreads();
    int C = (E + (int)gridDim.x - 1) / (int)gridDim.x;
    int e0 = b * C, e1 = min(E, e0 + C);
    for (int e = e0 + t; e < e1; e += 256) {
        int a = ei[e], c = ei[E + e];
        int s1 = atomicAdd(&cur[a >> GBITS], 1);
        bucket[s1] = ((unsigned)(a & 31) << 16) | (unsigned)c;
        int s2 = atomicAdd(&cur[c >> GBITS], 1);
        bucket[s2] = ((unsigned)(c & 31) << 16) | (unsigned)a;
    }
}

// ---------------------------------------------------------------------------
// P4 (fused): per group of 32 nodes — LDS bitmap dedup -> popcount -> dinv,
// then weighted colsum of those 32 x-rows -> partial. All atomics in LDS.
// ---------------------------------------------------------------------------
__global__ __launch_bounds__(256)
void k_dedup_colsum(const unsigned* __restrict__ bucket,
                    const int* __restrict__ gbase, const int* __restrict__ gend,
                    const float4* __restrict__ x4,
                    float* __restrict__ dinv, float4* __restrict__ partial4,
                    int n) {
    __shared__ unsigned bm[32 * WPR];     // 48128 B
    __shared__ float dloc[32];
    __shared__ float4 red[8][32];
    int g = blockIdx.x, t = threadIdx.x;

    for (int i = t; i < 32 * WPR; i += 256) bm[i] = 0;
    __syncthreads();

    int i0 = gbase[g], i1 = gend[g];
    for (int i = i0 + t; i < i1; i += 256) {
        unsigned w = bucket[i];
        atomicOr(&bm[(w >> 16) * WPR + ((w & 0xFFFFu) >> 5)], 1u << (w & 31));
    }
    __syncthreads();

    int wave = t >> 6, lane = t & 63;
    int words = (n + 31) >> 5;            // 375
    for (int lr = wave; lr < 32; lr += 4) {
        int node = g * 32 + lr;
        int cnt = 0;
        for (int w = lane; w < words; w += 64)
            cnt += __popc(bm[lr * WPR + w]);
        #pragma unroll
        for (int o = 32; o > 0; o >>= 1)
            cnt += __shfl_down(cnt, o, 64);
        if (lane == 0) {
            float dv = 1.0f / sqrtf((float)cnt);   // deg==0 -> inf, matches ref
            dloc[lr] = dv;
            if (node < n) dinv[node] = dv;
        }
    }
    __syncthreads();

    int c4 = t & 31, ro = t >> 5;         // ro 0..7
    float4 acc = make_float4(0.f, 0.f, 0.f, 0.f);
    for (int lr = ro; lr < 32; lr += 8) {
        int node = g * 32 + lr;
        if (node >= n) break;
        float dv = dloc[lr];
        float4 v = x4[(size_t)node * (F_IN / 4) + c4];
        acc.x += dv * v.x; acc.y += dv * v.y;
        acc.z += dv * v.z; acc.w += dv * v.w;
    }
    red[ro][c4] = acc;
    __syncthreads();
    if (ro == 0) {
        float4 s = red[0][c4];
        #pragma unroll
        for (int k = 1; k < 8; ++k) {
            float4 v = red[k][c4];
            s.x += v.x; s.y += v.y; s.z += v.z; s.w += v.w;
        }
        partial4[(size_t)g * (F_IN / 4) + c4] = s;
    }
}

// ---------------------------------------------------------------------------
// P5 (fused): every block redundantly reduces partials -> s[128] (fixed
// order => identical in all blocks => deterministic), computes
// agg = s·W (4-way k-split + LDS combine), then grid-strides the output:
// out[n,f] = dinv[n]*agg[f] + bias[f]. Replaces k_reduce_agg + k_outer.
// ---------------------------------------------------------------------------
__global__ __launch_bounds__(256)
void k_fused_out(const float4* __restrict__ partial4, int G,
                 const float* __restrict__ W, const float* __restrict__ bias,
                 const float* __restrict__ dinv,
                 float4* __restrict__ out4, int n) {
    __shared__ float4 red[8][32];
    __shared__ float s[F_IN];
    __shared__ float4 agg4[4][F_OUT / 4];
    int t = threadIdx.x;

    // Phase A: s = sum_g partial4[g][.]
    {
        int c4 = t & 31, ro = t >> 5;
        float4 acc = make_float4(0.f, 0.f, 0.f, 0.f);
        for (int g = ro; g < G; g += 8) {
            float4 v = partial4[(size_t)g * (F_IN / 4) + c4];
            acc.x += v.x; acc.y += v.y; acc.z += v.z; acc.w += v.w;
        }
        red[ro][c4] = acc;
        __syncthreads();
        if (ro == 0) {
            float4 v = red[0][c4];
            #pragma unroll
            for (int k = 1; k < 8; ++k) {
                float4 o = red[k][c4];
                v.x += o.x; v.y += o.y; v.z += o.z; v.w += o.w;
            }
            s[c4 * 4 + 0] = v.x; s[c4 * 4 + 1] = v.y;
            s[c4 * 4 + 2] = v.z; s[c4 * 4 + 3] = v.w;
        }
        __syncthreads();
    }

    // Phase B: agg = s . W   (W row-major [F_IN][F_OUT])
    {
        int f4 = t & 63;          // float4 col group
        int kg = t >> 6;          // 0..3
        const float4* W4 = (const float4*)W;
        float4 a = make_float4(0.f, 0.f, 0.f, 0.f);
        #pragma unroll 8
        for (int k = kg * 32; k < kg * 32 + 32; ++k) {
            float sk = s[k];      // LDS broadcast
            float4 w = W4[(size_t)k * (F_OUT / 4) + f4];
            a.x += sk * w.x; a.y += sk * w.y;
            a.z += sk * w.z; a.w += sk * w.w;
        }
        agg4[kg][f4] = a;
        __syncthreads();
    }

    // Phase C: output. f4 = i&63 is invariant (stride % 64 == 0).
    {
        int f4 = t & 63;
        float4 a0 = agg4[0][f4], a1 = agg4[1][f4],
               a2 = agg4[2][f4], a3 = agg4[3][f4];
        float4 ag;
        ag.x = a0.x + a1.x + a2.x + a3.x;
        ag.y = a0.y + a1.y + a2.y + a3.y;
        ag.z = a0.z + a1.z + a2.z + a3.z;
        ag.w = a0.w + a1.w + a2.w + a3.w;
        float4 b4 = ((const float4*)bias)[f4];
        int total4 = n * (F_OUT / 4);
        int gs = (int)gridDim.x * 256;
        for (int i = (int)blockIdx.x * 256 + t; i < total4; i += gs) {
            float d = dinv[i >> 6];           // 64 consecutive lanes share node
            float4 o;
            o.x = fmaf(d, ag.x, b4.x);
            o.y = fmaf(d, ag.y, b4.y);
            o.z = fmaf(d, ag.z, b4.z);
            o.w = fmaf(d, ag.w, b4.w);
            out4[i] = o;
        }
    }
}

// ===========================================================================
// Fallback (odd sizes / tiny workspace): round-4 global-bitmap path.
// ===========================================================================
__global__ __launch_bounds__(256)
void k_zero_simple(float4* __restrict__ p, size_t n4) {
    size_t i = (size_t)blockIdx.x * blockDim.x + threadIdx.x;
    size_t stride = (size_t)gridDim.x * blockDim.x;
    float4 z = make_float4(0.f, 0.f, 0.f, 0.f);
    for (; i < n4; i += stride) p[i] = z;
}
__global__ void k_set_bits_simple(const int* __restrict__ ei, int E,
                                  unsigned* __restrict__ bm, int r0, int r1,
                                  int row_words) {
    int e = blockIdx.x * blockDim.x + threadIdx.x;
    if (e >= E) return;
    int a = ei[e];
    int b = ei[E + e];
    if (a >= r0 && a < r1)
        atomicOr(&bm[(size_t)(a - r0) * row_words + (b >> 5)], 1u << (b & 31));
    if (b >= r0 && b < r1)
        atomicOr(&bm[(size_t)(b - r0) * row_words + (a >> 5)], 1u << (a & 31));
}
__global__ __launch_bounds__(256)
void k_degree_simple(const unsigned* __restrict__ bm, float* __restrict__ dinv,
                     int r0, int rows, int row_words) {
    int wave = threadIdx.x >> 6;
    int lane = threadIdx.x & 63;
    int row  = blockIdx.x * 4 + wave;
    if (row >= rows) return;
    const unsigned* p = bm + (size_t)row * row_words;
    int cnt = 0;
    for (int w = lane; w < row_words; w += 64)
        cnt += __popc(p[w]);
    #pragma unroll
    for (int off = 32; off > 0; off >>= 1)
        cnt += __shfl_down(cnt, off, 64);
    if (lane == 0)
        dinv[r0 + row] = 1.0f / sqrtf((float)cnt);
}
__global__ __launch_bounds__(256)
void k_colsum_simple(const float4* __restrict__ x4, const float* __restrict__ dinv,
                     float4* __restrict__ partial4, int n) {
    __shared__ float4 lds[8][32];
    int t = threadIdx.x;
    int c4 = t & 31;
    int ro = t >> 5;
    int rows_per = (n + (int)gridDim.x - 1) / (int)gridDim.x;
    int rbeg = blockIdx.x * rows_per;
    int rend = rbeg + rows_per; if (rend > n) rend = n;
    float4 acc = make_float4(0.f, 0.f, 0.f, 0.f);
    for (int r = rbeg + ro; r < rend; r += 8) {
        float dv = dinv[r];
        float4 v = x4[(size_t)r * (F_IN / 4) + c4];
        acc.x += dv * v.x; acc.y += dv * v.y;
        acc.z += dv * v.z; acc.w += dv * v.w;
    }
    lds[ro][c4] = acc;
    __syncthreads();
    if (ro == 0) {
        float4 s = lds[0][c4];
        #pragma unroll
        for (int g = 1; g < 8; ++g) {
            float4 v = lds[g][c4];
            s.x += v.x; s.y += v.y; s.z += v.z; s.w += v.w;
        }
        partial4[(size_t)blockIdx.x * (F_IN / 4) + c4] = s;
    }
}

// ---------------------------------------------------------------------------
static inline size_t align_up(size_t v, size_t a) { return (v + a - 1) & ~(a - 1); }

extern "C" void kernel_launch(void* const* d_in, const int* in_sizes, int n_in,
                              void* d_out, int out_size, void* d_ws, size_t ws_size,
                              hipStream_t stream) {
    const float* x    = (const float*)d_in[0];
    const int*   ei   = (const int*)  d_in[1];
    const float* W    = (const float*)d_in[2];
    const float* bias = (const float*)d_in[3];

    const int n = in_sizes[0] / F_IN;     // 12000
    const int E = in_sizes[1] / 2;        // 384000
    const int G = (n + 31) >> GBITS;      // 375

    char* ws = (char*)d_ws;
    size_t off_b = 0;
    float* dinv = (float*)(ws + off_b); off_b = align_up(off_b + (size_t)n * 4, 256);
    float4* partial4 = (float4*)(ws + off_b); off_b = align_up(off_b + (size_t)G * F_IN * 4, 256);
    int* counts_t = (int*)(ws + off_b); off_b = align_up(off_b + (size_t)G * NBLK * 4, 256);
    int* offs_t   = (int*)(ws + off_b); off_b = align_up(off_b + (size_t)G * NBLK * 4, 256);
    int* gtot     = (int*)(ws + off_b); off_b = align_up(off_b + (size_t)G * 4, 256);
    int* gbase    = (int*)(ws + off_b); off_b = align_up(off_b + (size_t)G * 4, 256);
    int* gend     = (int*)(ws + off_b); off_b = align_up(off_b + (size_t)G * 4, 256);
    unsigned* bucket = (unsigned*)(ws + off_b);
    size_t need = off_b + (size_t)2 * E * 4;

    bool fast = (G <= G_MAX) && (((n + 31) >> 5) <= WPR) && (n <= 65536) &&
                (need <= ws_size);

    if (fast) {
        k_count  <<<NBLK, 256, 0, stream>>>(ei, E, G, counts_t);
        k_prefix1<<<G,   NBLK, 0, stream>>>(counts_t, G, offs_t, gtot);
        k_scatter<<<NBLK, 256, 0, stream>>>(ei, E, G, offs_t, gtot, gbase, gend, bucket);
        k_dedup_colsum<<<G, 256, 0, stream>>>(bucket, gbase, gend,
                                              (const float4*)x, dinv, partial4, n);
        k_fused_out<<<320, 256, 0, stream>>>(partial4, G, W, bias, dinv,
                                             (float4*)d_out, n);
        return;
    }

    // ---- fallback: global-bitmap path ----
    const int row_words = (int)align_up((size_t)((n + 31) / 32), 64);
    const int NB = 512;
    size_t off_f = 0;
    float* dinv_f = (float*)(ws + off_f); off_f = align_up(off_f + (size_t)n * 4, 256);
    float4* part_f = (float4*)(ws + off_f); off_f = align_up(off_f + (size_t)NB * F_IN * 4, 256);
    unsigned* bm = (unsigned*)(ws + off_f);
    size_t avail = (ws_size > off_f) ? (ws_size - off_f) : 0;
    long long fit = (long long)(avail / ((size_t)row_words * 4));
    int rows_per_chunk = (fit >= n) ? n : (fit > 0 ? (int)fit : 1);
    for (int r0 = 0; r0 < n; r0 += rows_per_chunk) {
        int rows = n - r0; if (rows > rows_per_chunk) rows = rows_per_chunk;
        size_t n4 = (size_t)rows * row_words / 4;
        int zgrid = (int)((n4 + 255) / 256); if (zgrid > 2048) zgrid = 2048;
        k_zero_simple<<<zgrid, 256, 0, stream>>>((float4*)bm, n4);
        k_set_bits_simple<<<(E + 255) / 256, 256, 0, stream>>>(ei, E, bm, r0, r0 + rows, row_words);
        k_degree_simple<<<(rows + 3) / 4, 256, 0, stream>>>(bm, dinv_f, r0, rows, row_words);
    }
    k_colsum_simple<<<NB, 256, 0, stream>>>((const float4*)x, dinv_f, part_f, n);
    k_fused_out<<<320, 256, 0, stream>>>(part_f, NB, W, bias, dinv_f,
                                         (float4*)d_out, n);
}